// Round 1
// baseline (517.407 us; speedup 1.0000x reference)
//
#include <hip/hip_runtime.h>
#include <stdint.h>

typedef __attribute__((ext_vector_type(8))) short bf8;   // 8 bf16 (4 VGPRs)
typedef __attribute__((ext_vector_type(4))) float f4;
typedef unsigned short u16;

#define LDK 56            // GEMM LDS row stride (elems): 112B, 16B-aligned, 2-way banks
#define VTS 72            // V-transpose LDS row stride  : 144B, 16B-aligned
#define PLS 56            // P LDS row stride

static __device__ inline u16 f2bfbits(float f) {
    unsigned u = __float_as_uint(f);
    unsigned r = 0x7FFFu + ((u >> 16) & 1u);
    return (u16)((u + r) >> 16);
}

// ---------------- prep: fp32 -> bf16 ----------------
__global__ void cvt_bf16(const float* __restrict__ in, u16* __restrict__ out, int n) {
    int i = (blockIdx.x * 256 + threadIdx.x) * 4;
    if (i < n) {
        float4 v = *(const float4*)(in + i);
        ushort4 o;
        o.x = f2bfbits(v.x); o.y = f2bfbits(v.y);
        o.z = f2bfbits(v.z); o.w = f2bfbits(v.w);
        *(ushort4*)(out + i) = o;
    }
}

// ---------------- prep: W[K][N] fp32 -> WT[N][K] bf16 ----------------
__global__ void transpose4(const float* __restrict__ w0, const float* __restrict__ w1,
                           const float* __restrict__ w2, const float* __restrict__ w3,
                           u16* __restrict__ o0, u16* __restrict__ o1,
                           u16* __restrict__ o2, u16* __restrict__ o3) {
    __shared__ float tile[32][33];
    const float* w = blockIdx.z == 0 ? w0 : blockIdx.z == 1 ? w1 : blockIdx.z == 2 ? w2 : w3;
    u16* o = blockIdx.z == 0 ? o0 : blockIdx.z == 1 ? o1 : blockIdx.z == 2 ? o2 : o3;
    int bx = blockIdx.x * 32, by = blockIdx.y * 32;
    int tx = threadIdx.x, ty = threadIdx.y;
#pragma unroll
    for (int r = 0; r < 32; r += 8)
        tile[ty + r][tx] = w[(size_t)(by + ty + r) * 1024 + bx + tx];
    __syncthreads();
#pragma unroll
    for (int r = 0; r < 32; r += 8)
        o[(size_t)(bx + ty + r) * 1024 + by + tx] = f2bfbits(tile[tx][ty + r]);
}

// ---------------- bf16 MFMA GEMM: C[M=8192][N=1024] = A[M][1024] * BT[N][1024]^T + bias ----
// mode 0: write bf16 to [B,H,S,64] (QKV);  mode 1: write fp32 to [M][N] (final out)
__global__ __launch_bounds__(256) void gemm128(
    const u16* __restrict__ A, const u16* __restrict__ BT,
    const float* __restrict__ bias,
    u16* __restrict__ outb, float* __restrict__ outf, int mode) {
    __shared__ __align__(16) short As[128][LDK];
    __shared__ __align__(16) short Bs[128][LDK];
    const int tid = threadIdx.x;
    const int lane = tid & 63;
    const int l15 = lane & 15, lg = lane >> 4;
    const int wave = tid >> 6;
    const int wm = (wave >> 1) * 64, wn = (wave & 1) * 64;
    const int m0 = blockIdx.x * 128, n0 = blockIdx.y * 128;
    const int srow = tid >> 2;        // 0..63
    const int scol = (tid & 3) * 8;   // 0,8,16,24

    f4 acc[4][4] = {};

    for (int k0 = 0; k0 < 1024; k0 += 32) {
        bf8 a0 = *(const bf8*)(A + (size_t)(m0 + srow) * 1024 + k0 + scol);
        bf8 a1 = *(const bf8*)(A + (size_t)(m0 + srow + 64) * 1024 + k0 + scol);
        bf8 b0 = *(const bf8*)(BT + (size_t)(n0 + srow) * 1024 + k0 + scol);
        bf8 b1 = *(const bf8*)(BT + (size_t)(n0 + srow + 64) * 1024 + k0 + scol);
        __syncthreads();              // prior-iter fragment reads done before overwrite
        *(bf8*)(&As[srow][scol]) = a0;
        *(bf8*)(&As[srow + 64][scol]) = a1;
        *(bf8*)(&Bs[srow][scol]) = b0;
        *(bf8*)(&Bs[srow + 64][scol]) = b1;
        __syncthreads();
        bf8 af[4], bfr[4];
#pragma unroll
        for (int i = 0; i < 4; ++i) af[i] = *(const bf8*)(&As[wm + i * 16 + l15][lg * 8]);
#pragma unroll
        for (int j = 0; j < 4; ++j) bfr[j] = *(const bf8*)(&Bs[wn + j * 16 + l15][lg * 8]);
#pragma unroll
        for (int i = 0; i < 4; ++i)
#pragma unroll
            for (int j = 0; j < 4; ++j)
                acc[i][j] = __builtin_amdgcn_mfma_f32_16x16x32_bf16(af[i], bfr[j], acc[i][j], 0, 0, 0);
    }

    float bj[4];
#pragma unroll
    for (int j = 0; j < 4; ++j) bj[j] = bias[n0 + wn + j * 16 + l15];

    if (mode == 0) {
#pragma unroll
        for (int i = 0; i < 4; ++i) {
            int gm = m0 + wm + i * 16 + lg * 4;
#pragma unroll
            for (int j = 0; j < 4; ++j) {
                int gn = n0 + wn + j * 16 + l15;
                int h = gn >> 6, d = gn & 63;
#pragma unroll
                for (int r = 0; r < 4; ++r) {
                    int m = gm + r;
                    int b_ = m >> 11, s = m & 2047;
                    float vv = acc[i][j][r] + bj[j];
                    outb[(((size_t)(b_ * 16 + h) * 2048) + s) * 64 + d] = f2bfbits(vv);
                }
            }
        }
    } else {
#pragma unroll
        for (int i = 0; i < 4; ++i) {
            int gm = m0 + wm + i * 16 + lg * 4;
#pragma unroll
            for (int j = 0; j < 4; ++j) {
                int gn = n0 + wn + j * 16 + l15;
#pragma unroll
                for (int r = 0; r < 4; ++r)
                    outf[(size_t)(gm + r) * 1024 + gn] = acc[i][j][r] + bj[j];
            }
        }
    }
}

// ---------------- flash attention, bf16 MFMA, fp32 softmax ----------------
// grid: (S/64 = 32 q-tiles, B*H = 64); block 256 = 4 waves x 16 q-rows
__global__ __launch_bounds__(256) void attn(
    const u16* __restrict__ Q, const u16* __restrict__ K, const u16* __restrict__ V,
    u16* __restrict__ ctx) {
    __shared__ __align__(16) short VT[64][VTS];      // V^T tile: [d][t_local]
    __shared__ __align__(16) short Pl[4][16][PLS];   // per-wave P tile: [q][t32]
    const int tid = threadIdx.x, lane = tid & 63, wave = tid >> 6;
    const int l15 = lane & 15, lg = lane >> 4;
    const int qt = blockIdx.x, bh = blockIdx.y;
    const u16* Qh = Q + (size_t)bh * 2048 * 64;
    const u16* Kh = K + (size_t)bh * 2048 * 64;
    const u16* Vh = V + (size_t)bh * 2048 * 64;
    const int q0 = qt * 64 + wave * 16;

    bf8 qf0 = *(const bf8*)(Qh + (size_t)(q0 + l15) * 64 + lg * 8);
    bf8 qf1 = *(const bf8*)(Qh + (size_t)(q0 + l15) * 64 + 32 + lg * 8);

    f4 octx[4] = {};
    float mrow[4], lrow[4];
#pragma unroll
    for (int r = 0; r < 4; ++r) { mrow[r] = -INFINITY; lrow[r] = 0.f; }

    for (int t0 = 0; t0 < 2048; t0 += 64) {
        __syncthreads();   // prior-iter VT reads complete
#pragma unroll
        for (int rr = 0; rr < 2; ++rr) {
            int t = rr * 32 + (tid >> 3);
            int d0 = (tid & 7) * 8;
            bf8 vv = *(const bf8*)(Vh + (size_t)(t0 + t) * 64 + d0);
#pragma unroll
            for (int e = 0; e < 8; ++e) VT[d0 + e][t] = vv[e];
        }
        __syncthreads();

#pragma unroll
        for (int sub = 0; sub < 2; ++sub) {
            int ts = t0 + sub * 32;
            f4 sa[2];
#pragma unroll
            for (int u = 0; u < 2; ++u) {
                bf8 kf0 = *(const bf8*)(Kh + (size_t)(ts + u * 16 + l15) * 64 + lg * 8);
                bf8 kf1 = *(const bf8*)(Kh + (size_t)(ts + u * 16 + l15) * 64 + 32 + lg * 8);
                f4 z = {};
                z = __builtin_amdgcn_mfma_f32_16x16x32_bf16(qf0, kf0, z, 0, 0, 0);
                z = __builtin_amdgcn_mfma_f32_16x16x32_bf16(qf1, kf1, z, 0, 0, 0);
                sa[u] = z;
            }
            float fac[4];
#pragma unroll
            for (int r = 0; r < 4; ++r) {
                float s0 = sa[0][r] * 0.125f;
                float s1 = sa[1][r] * 0.125f;
                float mx = fmaxf(s0, s1);
                mx = fmaxf(mx, __shfl_xor(mx, 1));
                mx = fmaxf(mx, __shfl_xor(mx, 2));
                mx = fmaxf(mx, __shfl_xor(mx, 4));
                mx = fmaxf(mx, __shfl_xor(mx, 8));
                float mnew = fmaxf(mrow[r], mx);
                fac[r] = __expf(mrow[r] - mnew);
                mrow[r] = mnew;
                float p0 = __expf(s0 - mnew);
                float p1 = __expf(s1 - mnew);
                float ps = p0 + p1;
                ps += __shfl_xor(ps, 1);
                ps += __shfl_xor(ps, 2);
                ps += __shfl_xor(ps, 4);
                ps += __shfl_xor(ps, 8);
                lrow[r] = lrow[r] * fac[r] + ps;
                Pl[wave][lg * 4 + r][l15] = f2bfbits(p0);
                Pl[wave][lg * 4 + r][16 + l15] = f2bfbits(p1);
            }
#pragma unroll
            for (int j = 0; j < 4; ++j)
#pragma unroll
                for (int r = 0; r < 4; ++r) octx[j][r] *= fac[r];
            asm volatile("s_waitcnt lgkmcnt(0)" ::: "memory");
            bf8 pf = *(const bf8*)(&Pl[wave][l15][lg * 8]);
#pragma unroll
            for (int j = 0; j < 4; ++j) {
                bf8 vf = *(const bf8*)(&VT[j * 16 + l15][sub * 32 + lg * 8]);
                octx[j] = __builtin_amdgcn_mfma_f32_16x16x32_bf16(pf, vf, octx[j], 0, 0, 0);
            }
        }
    }

    const int b_ = bh >> 4, h = bh & 15;
    const size_t base = (size_t)b_ * 2048 * 1024 + (size_t)h * 64;
#pragma unroll
    for (int j = 0; j < 4; ++j)
#pragma unroll
        for (int r = 0; r < 4; ++r) {
            int s = q0 + lg * 4 + r;
            int d = j * 16 + l15;
            float val = octx[j][r] / lrow[r];
            ctx[base + (size_t)s * 1024 + d] = f2bfbits(val);
        }
}

extern "C" void kernel_launch(void* const* d_in, const int* in_sizes, int n_in,
                              void* d_out, int out_size, void* d_ws, size_t ws_size,
                              hipStream_t stream) {
    const float* x  = (const float*)d_in[0];
    const float* wq = (const float*)d_in[1];
    const float* bq = (const float*)d_in[2];
    const float* wk = (const float*)d_in[3];
    const float* bk = (const float*)d_in[4];
    const float* wv = (const float*)d_in[5];
    const float* bv = (const float*)d_in[6];
    const float* wo = (const float*)d_in[7];
    const float* bo = (const float*)d_in[8];
    float* out = (float*)d_out;

    char* ws = (char*)d_ws;
    u16* xb  = (u16*)ws;                               // 8192*1024 bf16 = 16 MB
    u16* wtq = (u16*)(ws + (size_t)(16 << 20));        // 4 x 1024*1024 bf16 = 8 MB
    u16* wtk = wtq + 1024 * 1024;
    u16* wtv = wtk + 1024 * 1024;
    u16* wto = wtv + 1024 * 1024;
    u16* q   = (u16*)(ws + (size_t)(24 << 20));        // [B,H,S,64] bf16, 16 MB
    u16* k   = q + 8192 * 1024;
    u16* v   = k + 8192 * 1024;
    u16* ctx = v + 8192 * 1024;                        // [B,S,1024] bf16, 16 MB

    hipLaunchKernelGGL(cvt_bf16, dim3(8192), dim3(256), 0, stream, x, xb, 8192 * 1024);
    hipLaunchKernelGGL(transpose4, dim3(32, 32, 4), dim3(32, 8), 0, stream,
                       wq, wk, wv, wo, wtq, wtk, wtv, wto);
    dim3 gg(64, 8);
    hipLaunchKernelGGL(gemm128, gg, dim3(256), 0, stream, xb, wtq, bq, q, (float*)nullptr, 0);
    hipLaunchKernelGGL(gemm128, gg, dim3(256), 0, stream, xb, wtk, bk, k, (float*)nullptr, 0);
    hipLaunchKernelGGL(gemm128, gg, dim3(256), 0, stream, xb, wtv, bv, v, (float*)nullptr, 0);
    hipLaunchKernelGGL(attn, dim3(32, 64), dim3(256), 0, stream, q, k, v, ctx);
    hipLaunchKernelGGL(gemm128, gg, dim3(256), 0, stream, ctx, wto, bo, (u16*)nullptr, out, 1);
}

// Round 2
// 359.955 us; speedup vs baseline: 1.4374x; 1.4374x over previous
//
#include <hip/hip_runtime.h>
#include <stdint.h>

typedef __attribute__((ext_vector_type(8))) short bf8;    // 8 bf16 (4 VGPRs)
typedef __attribute__((ext_vector_type(4))) float f4;
typedef __attribute__((ext_vector_type(16))) float f16v;
typedef __attribute__((ext_vector_type(4))) int i4;
typedef unsigned short u16;

#define LDK 56            // GEMM LDS row stride (elems): 112B, 16B-aligned, 2-way banks

static __device__ inline u16 f2bfbits(float f) {
    unsigned u = __float_as_uint(f);
    unsigned r = 0x7FFFu + ((u >> 16) & 1u);
    return (u16)((u + r) >> 16);
}

// packed f32x2 -> bf16x2 (RNE), low word = first arg
static __device__ inline int cvtpk(float lo, float hi) {
    int r;
    asm("v_cvt_pk_bf16_f32 %0, %1, %2" : "=v"(r) : "v"(lo), "v"(hi));
    return r;
}

// ---------------- prep: fp32 -> bf16 ----------------
__global__ void cvt_bf16(const float* __restrict__ in, u16* __restrict__ out, int n) {
    int i = (blockIdx.x * 256 + threadIdx.x) * 4;
    if (i < n) {
        float4 v = *(const float4*)(in + i);
        ushort4 o;
        o.x = f2bfbits(v.x); o.y = f2bfbits(v.y);
        o.z = f2bfbits(v.z); o.w = f2bfbits(v.w);
        *(ushort4*)(out + i) = o;
    }
}

// ---------------- prep: W[K][N] fp32 -> WT[N][K] bf16 ----------------
__global__ void transpose4(const float* __restrict__ w0, const float* __restrict__ w1,
                           const float* __restrict__ w2, const float* __restrict__ w3,
                           u16* __restrict__ o0, u16* __restrict__ o1,
                           u16* __restrict__ o2, u16* __restrict__ o3) {
    __shared__ float tile[32][33];
    const float* w = blockIdx.z == 0 ? w0 : blockIdx.z == 1 ? w1 : blockIdx.z == 2 ? w2 : w3;
    u16* o = blockIdx.z == 0 ? o0 : blockIdx.z == 1 ? o1 : blockIdx.z == 2 ? o2 : o3;
    int bx = blockIdx.x * 32, by = blockIdx.y * 32;
    int tx = threadIdx.x, ty = threadIdx.y;
#pragma unroll
    for (int r = 0; r < 32; r += 8)
        tile[ty + r][tx] = w[(size_t)(by + ty + r) * 1024 + bx + tx];
    __syncthreads();
#pragma unroll
    for (int r = 0; r < 32; r += 8)
        o[(size_t)(bx + ty + r) * 1024 + by + tx] = f2bfbits(tile[tx][ty + r]);
}

// ---------------- bf16 MFMA GEMM: C[8192][1024] = A * BT^T + bias ----------------
// mode 0: bf16 [B,H,S,64] (K);  mode 2: same but x0.125 (Q);
// mode 3: bf16 V^T [B,H,64,S];  mode 1: fp32 [M][N] (final out)
__global__ __launch_bounds__(256) void gemm128(
    const u16* __restrict__ A, const u16* __restrict__ BT,
    const float* __restrict__ bias,
    u16* __restrict__ outb, float* __restrict__ outf, int mode) {
    __shared__ __align__(16) short As[128][LDK];
    __shared__ __align__(16) short Bs[128][LDK];
    const int tid = threadIdx.x;
    const int lane = tid & 63;
    const int l15 = lane & 15, lg = lane >> 4;
    const int wave = tid >> 6;
    const int wm = (wave >> 1) * 64, wn = (wave & 1) * 64;
    const int m0 = blockIdx.x * 128, n0 = blockIdx.y * 128;
    const int srow = tid >> 2;
    const int scol = (tid & 3) * 8;

    f4 acc[4][4] = {};

    for (int k0 = 0; k0 < 1024; k0 += 32) {
        bf8 a0 = *(const bf8*)(A + (size_t)(m0 + srow) * 1024 + k0 + scol);
        bf8 a1 = *(const bf8*)(A + (size_t)(m0 + srow + 64) * 1024 + k0 + scol);
        bf8 b0 = *(const bf8*)(BT + (size_t)(n0 + srow) * 1024 + k0 + scol);
        bf8 b1 = *(const bf8*)(BT + (size_t)(n0 + srow + 64) * 1024 + k0 + scol);
        __syncthreads();
        *(bf8*)(&As[srow][scol]) = a0;
        *(bf8*)(&As[srow + 64][scol]) = a1;
        *(bf8*)(&Bs[srow][scol]) = b0;
        *(bf8*)(&Bs[srow + 64][scol]) = b1;
        __syncthreads();
        bf8 af[4], bfr[4];
#pragma unroll
        for (int i = 0; i < 4; ++i) af[i] = *(const bf8*)(&As[wm + i * 16 + l15][lg * 8]);
#pragma unroll
        for (int j = 0; j < 4; ++j) bfr[j] = *(const bf8*)(&Bs[wn + j * 16 + l15][lg * 8]);
#pragma unroll
        for (int i = 0; i < 4; ++i)
#pragma unroll
            for (int j = 0; j < 4; ++j)
                acc[i][j] = __builtin_amdgcn_mfma_f32_16x16x32_bf16(af[i], bfr[j], acc[i][j], 0, 0, 0);
    }

    float bj[4];
#pragma unroll
    for (int j = 0; j < 4; ++j) bj[j] = bias[n0 + wn + j * 16 + l15];
    const float sc = (mode == 2) ? 0.125f : 1.0f;

    if (mode == 1) {
#pragma unroll
        for (int i = 0; i < 4; ++i) {
            int gm = m0 + wm + i * 16 + lg * 4;
#pragma unroll
            for (int j = 0; j < 4; ++j) {
                int gn = n0 + wn + j * 16 + l15;
#pragma unroll
                for (int r = 0; r < 4; ++r)
                    outf[(size_t)(gm + r) * 1024 + gn] = acc[i][j][r] + bj[j];
            }
        }
    } else if (mode == 3) {          // V^T: [B,H,64,S], 8B packed stores (r -> s consecutive)
#pragma unroll
        for (int i = 0; i < 4; ++i) {
            int gm = m0 + wm + i * 16 + lg * 4;
            int b_ = gm >> 11, s0 = gm & 2047;
#pragma unroll
            for (int j = 0; j < 4; ++j) {
                int gn = n0 + wn + j * 16 + l15;
                int h = gn >> 6, d = gn & 63;
                ushort4 w;
                w.x = f2bfbits(acc[i][j][0] + bj[j]);
                w.y = f2bfbits(acc[i][j][1] + bj[j]);
                w.z = f2bfbits(acc[i][j][2] + bj[j]);
                w.w = f2bfbits(acc[i][j][3] + bj[j]);
                *(ushort4*)(outb + ((size_t)(b_ * 16 + h) * 64 + d) * 2048 + s0) = w;
            }
        }
    } else {                         // Q/K: [B,H,S,64]
#pragma unroll
        for (int i = 0; i < 4; ++i) {
            int gm = m0 + wm + i * 16 + lg * 4;
#pragma unroll
            for (int j = 0; j < 4; ++j) {
                int gn = n0 + wn + j * 16 + l15;
                int h = gn >> 6, d = gn & 63;
#pragma unroll
                for (int r = 0; r < 4; ++r) {
                    int m = gm + r;
                    int b_ = m >> 11, s = m & 2047;
                    float vv = (acc[i][j][r] + bj[j]) * sc;
                    outb[(((size_t)(b_ * 16 + h) * 2048) + s) * 64 + d] = f2bfbits(vv);
                }
            }
        }
    }
}

// ---------------- flash attention: swapped QK^T, 32x32x16 MFMA, no LDS ----------------
// grid (2048/128=16, B*H=64), block 256 = 4 independent waves x 32 q-rows.
// Q pre-scaled by 0.125 in its GEMM epilogue. V supplied transposed [B,H,64,S].
// Per lane: q = lane&31 (fixed). S^T=mfma(K,Q): reg r -> t=(r&3)+8*(r>>2)+4*hi.
// ctx^T=mfma(V^T,P^T): reg r -> d=(r&3)+8*(r>>2)+4*hi (+32*dtile); col=q.
__global__ __launch_bounds__(256) void attn(
    const u16* __restrict__ Q, const u16* __restrict__ K, const u16* __restrict__ VT,
    u16* __restrict__ ctx) {
    const int lane = threadIdx.x & 63;
    const int wave = threadIdx.x >> 6;
    const int l31 = lane & 31;
    const int hi = lane >> 5;
    const int bh = blockIdx.y;
    const int q0 = blockIdx.x * 128 + wave * 32;

    const u16* Qh = Q + ((size_t)bh * 2048 + q0 + l31) * 64;
    const u16* Kh = K + (size_t)bh * 2048 * 64;
    const u16* Vh = VT + (size_t)bh * 64 * 2048;

    bf8 qf[4];
#pragma unroll
    for (int c = 0; c < 4; ++c) qf[c] = *(const bf8*)(Qh + c * 16 + hi * 8);

    f16v oc0 = {}, oc1 = {};
    float m = -INFINITY, l = 0.f;

    bf8 kf[4];
#pragma unroll
    for (int c = 0; c < 4; ++c) kf[c] = *(const bf8*)(Kh + (size_t)l31 * 64 + c * 16 + hi * 8);

    for (int t0 = 0; t0 < 2048; t0 += 32) {
        // V^T fragments for this tile (in flight through QK^T + softmax)
        bf8 vf[4];
#pragma unroll
        for (int dt = 0; dt < 2; ++dt)
#pragma unroll
            for (int tc = 0; tc < 2; ++tc)
                vf[dt * 2 + tc] = *(const bf8*)(Vh + (size_t)(dt * 32 + l31) * 2048 + t0 + tc * 16 + hi * 8);

        // S^T[t][q] for 32 t
        f16v s = {};
#pragma unroll
        for (int c = 0; c < 4; ++c)
            s = __builtin_amdgcn_mfma_f32_32x32x16_bf16(kf[c], qf[c], s, 0, 0, 0);

        // prefetch next K tile (in flight through softmax + PV)
        if (t0 + 32 < 2048) {
#pragma unroll
            for (int c = 0; c < 4; ++c)
                kf[c] = *(const bf8*)(Kh + (size_t)(t0 + 32 + l31) * 64 + c * 16 + hi * 8);
        }

        // online softmax, lane-local over 16 regs + one cross-half exchange
        float pmax = s[0];
#pragma unroll
        for (int r = 1; r < 16; ++r) pmax = fmaxf(pmax, s[r]);
        pmax = fmaxf(pmax, __shfl_xor(pmax, 32));
        if (!__all(pmax <= m + 8.f)) {        // defer-max (T13)
            float mnew = fmaxf(m, pmax);
            float fac = __expf(m - mnew);
#pragma unroll
            for (int r = 0; r < 16; ++r) { oc0[r] *= fac; oc1[r] *= fac; }
            l *= fac; m = mnew;
        }
        float ps = 0.f;
#pragma unroll
        for (int r = 0; r < 16; ++r) { s[r] = __expf(s[r] - m); ps += s[r]; }
        ps += __shfl_xor(ps, 32);
        l += ps;

        // P -> bf16 B-fragment words: word j = k-elems (2j,2j+1), k = hi*8+e
        int u0 = cvtpk(s[0], s[1]),   v0 = cvtpk(s[4], s[5]);
        int u1 = cvtpk(s[2], s[3]),   v1 = cvtpk(s[6], s[7]);
        int u2 = cvtpk(s[8], s[9]),   v2 = cvtpk(s[12], s[13]);
        int u3 = cvtpk(s[10], s[11]), v3 = cvtpk(s[14], s[15]);
        int su0 = __shfl_xor(u0, 32), sv0 = __shfl_xor(v0, 32);
        int su1 = __shfl_xor(u1, 32), sv1 = __shfl_xor(v1, 32);
        int su2 = __shfl_xor(u2, 32), sv2 = __shfl_xor(v2, 32);
        int su3 = __shfl_xor(u3, 32), sv3 = __shfl_xor(v3, 32);
        i4 pw0i, pw1i;
        pw0i[0] = hi ? sv0 : u0;   // {lo:[t0,t1],  hi:[t8,t9]}
        pw0i[1] = hi ? sv1 : u1;   // {lo:[t2,t3],  hi:[t10,t11]}
        pw0i[2] = hi ? v0 : su0;   // {lo:[t4,t5],  hi:[t12,t13]}
        pw0i[3] = hi ? v1 : su1;   // {lo:[t6,t7],  hi:[t14,t15]}
        pw1i[0] = hi ? sv2 : u2;
        pw1i[1] = hi ? sv3 : u3;
        pw1i[2] = hi ? v2 : su2;
        pw1i[3] = hi ? v3 : su3;
        union { i4 i; bf8 h; } pw0, pw1;
        pw0.i = pw0i; pw1.i = pw1i;

        // ctx^T += V^T-tile * P^T
        oc0 = __builtin_amdgcn_mfma_f32_32x32x16_bf16(vf[0], pw0.h, oc0, 0, 0, 0);
        oc0 = __builtin_amdgcn_mfma_f32_32x32x16_bf16(vf[1], pw1.h, oc0, 0, 0, 0);
        oc1 = __builtin_amdgcn_mfma_f32_32x32x16_bf16(vf[2], pw0.h, oc1, 0, 0, 0);
        oc1 = __builtin_amdgcn_mfma_f32_32x32x16_bf16(vf[3], pw1.h, oc1, 0, 0, 0);
    }

    const float rl = 1.f / l;
    const int b_ = bh >> 4, h = bh & 15;
    u16* Cr = ctx + ((size_t)(b_ * 2048) + q0 + l31) * 1024 + h * 64;
#pragma unroll
    for (int g = 0; g < 4; ++g) {
        ushort4 w;
        w.x = f2bfbits(oc0[g * 4 + 0] * rl);
        w.y = f2bfbits(oc0[g * 4 + 1] * rl);
        w.z = f2bfbits(oc0[g * 4 + 2] * rl);
        w.w = f2bfbits(oc0[g * 4 + 3] * rl);
        *(ushort4*)(Cr + g * 8 + hi * 4) = w;
    }
#pragma unroll
    for (int g = 0; g < 4; ++g) {
        ushort4 w;
        w.x = f2bfbits(oc1[g * 4 + 0] * rl);
        w.y = f2bfbits(oc1[g * 4 + 1] * rl);
        w.z = f2bfbits(oc1[g * 4 + 2] * rl);
        w.w = f2bfbits(oc1[g * 4 + 3] * rl);
        *(ushort4*)(Cr + 32 + g * 8 + hi * 4) = w;
    }
}

extern "C" void kernel_launch(void* const* d_in, const int* in_sizes, int n_in,
                              void* d_out, int out_size, void* d_ws, size_t ws_size,
                              hipStream_t stream) {
    const float* x  = (const float*)d_in[0];
    const float* wq = (const float*)d_in[1];
    const float* bq = (const float*)d_in[2];
    const float* wk = (const float*)d_in[3];
    const float* bk = (const float*)d_in[4];
    const float* wv = (const float*)d_in[5];
    const float* bv = (const float*)d_in[6];
    const float* wo = (const float*)d_in[7];
    const float* bo = (const float*)d_in[8];
    float* out = (float*)d_out;

    char* ws = (char*)d_ws;
    u16* xb  = (u16*)ws;                               // 16 MB
    u16* wtq = (u16*)(ws + (size_t)(16 << 20));        // 4 x 2 MB
    u16* wtk = wtq + 1024 * 1024;
    u16* wtv = wtk + 1024 * 1024;
    u16* wto = wtv + 1024 * 1024;
    u16* q   = (u16*)(ws + (size_t)(24 << 20));        // [B,H,S,64]  16 MB (x0.125)
    u16* k   = q + 8192 * 1024;                        // [B,H,S,64]  16 MB
    u16* vt  = k + 8192 * 1024;                        // [B,H,64,S]  16 MB
    u16* ctx = vt + 8192 * 1024;                       // [B,S,1024]  16 MB

    hipLaunchKernelGGL(cvt_bf16, dim3(8192), dim3(256), 0, stream, x, xb, 8192 * 1024);
    hipLaunchKernelGGL(transpose4, dim3(32, 32, 4), dim3(32, 8), 0, stream,
                       wq, wk, wv, wo, wtq, wtk, wtv, wto);
    dim3 gg(64, 8);
    hipLaunchKernelGGL(gemm128, gg, dim3(256), 0, stream, xb, wtq, bq, q,  (float*)nullptr, 2);
    hipLaunchKernelGGL(gemm128, gg, dim3(256), 0, stream, xb, wtk, bk, k,  (float*)nullptr, 0);
    hipLaunchKernelGGL(gemm128, gg, dim3(256), 0, stream, xb, wtv, bv, vt, (float*)nullptr, 3);
    hipLaunchKernelGGL(attn, dim3(16, 64), dim3(256), 0, stream, q, k, vt, ctx);
    hipLaunchKernelGGL(gemm128, gg, dim3(256), 0, stream, ctx, wto, bo, (u16*)nullptr, out, 1);
}